// Round 1
// baseline (229.119 us; speedup 1.0000x reference)
//
#include <hip/hip_runtime.h>
#include <hip/hip_bf16.h>

#define NROW 8192
#define FINC 256
#define FOUTC 256
#define BM 32
#define BK 64
#define NT (NROW / BK)

typedef __attribute__((ext_vector_type(8))) short bf16x8;
typedef __attribute__((ext_vector_type(4))) float f32x4;

__device__ __forceinline__ unsigned short f2bf(float f) {
  unsigned u = __float_as_uint(f);
  u += 0x7fffu + ((u >> 16) & 1u);   // round-to-nearest-even
  return (unsigned short)(u >> 16);
}
__device__ __forceinline__ float bf2f(unsigned short h) {
  return __uint_as_float(((unsigned)h) << 16);
}

// ---- kernel 1: D[i] = 1/sqrt(1 + sum_j adj[i][j]) ----
__global__ __launch_bounds__(256) void rowsum_kernel(const float* __restrict__ adj,
                                                     float* __restrict__ D) {
  const int row = blockIdx.x;
  const float4* p = reinterpret_cast<const float4*>(adj + (size_t)row * NROW);
  float s = 0.f;
#pragma unroll
  for (int i = 0; i < 8; ++i) {
    float4 v = p[threadIdx.x + i * 256];
    s += (v.x + v.y) + (v.z + v.w);
  }
#pragma unroll
  for (int off = 32; off > 0; off >>= 1) s += __shfl_down(s, off, 64);
  __shared__ float red[4];
  const int lane = threadIdx.x & 63, w = threadIdx.x >> 6;
  if (lane == 0) red[w] = s;
  __syncthreads();
  if (threadIdx.x == 0) {
    float t = red[0] + red[1] + red[2] + red[3] + 1.0f;
    D[row] = 1.0f / sqrtf(t);
  }
}

// ---- kernel 2: s2T[f][j] = bf16( D[j] * (x @ W)[j][f] ) ----
__global__ __launch_bounds__(256) void support_kernel(const float* __restrict__ x,
                                                      const float* __restrict__ W,
                                                      const float* __restrict__ D,
                                                      unsigned short* __restrict__ s2T) {
  __shared__ float xs[32][FINC];
  const int t = threadIdx.x;
  const int r0 = blockIdx.x * 32;
  {
    const float4* xg = reinterpret_cast<const float4*>(x + (size_t)r0 * FINC);
    float4* xl = reinterpret_cast<float4*>(&xs[0][0]);
#pragma unroll
    for (int i = 0; i < 8; ++i) xl[t + i * 256] = xg[t + i * 256];
  }
  __syncthreads();
  const int w = t >> 6, l = t & 63;
  float acc[8][4] = {};
  const float4* W4 = reinterpret_cast<const float4*>(W);
#pragma unroll 4
  for (int k = 0; k < FINC; ++k) {
    float4 wv = W4[k * 64 + l];
#pragma unroll
    for (int m = 0; m < 8; ++m) {
      float xv = xs[w * 8 + m][k];
      acc[m][0] = fmaf(xv, wv.x, acc[m][0]);
      acc[m][1] = fmaf(xv, wv.y, acc[m][1]);
      acc[m][2] = fmaf(xv, wv.z, acc[m][2]);
      acc[m][3] = fmaf(xv, wv.w, acc[m][3]);
    }
  }
#pragma unroll
  for (int m = 0; m < 8; ++m) {
    const int j = r0 + w * 8 + m;
    const float d = D[j];
    const int f0 = l * 4;
#pragma unroll
    for (int q = 0; q < 4; ++q)
      s2T[(size_t)(f0 + q) * NROW + j] = f2bf(d * acc[m][q]);
  }
}

// ---- kernel 3: out[i][f] = relu( D[i]*( sum_j adj_bf16[i][j]*s2T[f][j] + s2T[f][i] ) + b[f] ) ----
__global__ __launch_bounds__(512) void gcn_gemm_kernel(const float* __restrict__ adj,
                                                       const unsigned short* __restrict__ s2T,
                                                       const float* __restrict__ D,
                                                       const float* __restrict__ bias,
                                                       float* __restrict__ out) {
  // A: [32 rows][64 k] bf16, B: [256 n][64 k] bf16, both XOR-swizzled (kbyte ^= (row&7)<<4)
  __shared__ __align__(16) unsigned short Asw[2][BM * BK];     // 4 KB each
  __shared__ __align__(16) unsigned short Bsw[2][FOUTC * BK];  // 32 KB each

  const int t = threadIdx.x;
  const int wid = t >> 6;
  const int l = t & 63;
  const int bm0 = blockIdx.x * BM;

  // A staging: thread -> (row = t>>4, 4 consecutive fp32 at k0=(t&15)*4)
  const int ar = t >> 4;
  const int akb = (t & 15) * 8;  // byte offset of the 8 bf16 bytes within row
  const unsigned aoff = (unsigned)(ar * 128 + (akb ^ ((ar & 7) << 4)));
  const float4* arow = reinterpret_cast<const float4*>(adj + (size_t)(bm0 + ar) * NROW) + (t & 15);

  // B staging via global_load_lds: 4 chunks of 1KB per wave; lane l -> row c*8+(l>>3)
  const int bn = l >> 3;
  const unsigned bks = (unsigned)(((l & 7) * 16) ^ (bn << 4));  // pre-swizzled source kbyte

  f32x4 acc[2][2] = {};

  const unsigned swz = (unsigned)((l & 7) << 4);
  const int fr = l & 15;
  const unsigned kb = (unsigned)((l >> 4) * 16);

  auto stageB = [&](int p, int kt) {
#pragma unroll
    for (int i = 0; i < 4; ++i) {
      const int c = wid * 4 + i;
      const int n = c * 8 + bn;
      const unsigned short* src = s2T + (size_t)n * NROW + (size_t)kt * BK;
      __builtin_amdgcn_global_load_lds(
          (const __attribute__((address_space(1))) unsigned int*)((const char*)src + bks),
          (__attribute__((address_space(3))) unsigned int*)((char*)&Bsw[p][0] + c * 1024),
          16, 0, 0);
    }
  };

  // prologue: stage kt=0 into buffer 0
  {
    float4 av = arow[0];
    stageB(0, 0);
    ushort4 ab;
    ab.x = f2bf(av.x); ab.y = f2bf(av.y); ab.z = f2bf(av.z); ab.w = f2bf(av.w);
    *reinterpret_cast<ushort4*>((char*)&Asw[0][0] + aoff) = ab;
  }
  __syncthreads();

  int p = 0;
  for (int kt = 0; kt < NT; ++kt) {
    float4 av;
    const bool more = (kt + 1) < NT;
    if (more) {
      av = arow[(kt + 1) * 16];
      stageB(p ^ 1, kt + 1);
    }
#pragma unroll
    for (int kk = 0; kk < 2; ++kk) {
      const unsigned kx = ((unsigned)(kk * 64) + kb) ^ swz;
      const char* Ab = (const char*)&Asw[p][0];
      const char* Bb = (const char*)&Bsw[p][0];
      const int nb = wid * 32;
      bf16x8 a0 = *reinterpret_cast<const bf16x8*>(Ab + fr * 128 + kx);
      bf16x8 a1 = *reinterpret_cast<const bf16x8*>(Ab + (fr + 16) * 128 + kx);
      bf16x8 b0 = *reinterpret_cast<const bf16x8*>(Bb + (nb + fr) * 128 + kx);
      bf16x8 b1 = *reinterpret_cast<const bf16x8*>(Bb + (nb + 16 + fr) * 128 + kx);
      acc[0][0] = __builtin_amdgcn_mfma_f32_16x16x32_bf16(a0, b0, acc[0][0], 0, 0, 0);
      acc[0][1] = __builtin_amdgcn_mfma_f32_16x16x32_bf16(a0, b1, acc[0][1], 0, 0, 0);
      acc[1][0] = __builtin_amdgcn_mfma_f32_16x16x32_bf16(a1, b0, acc[1][0], 0, 0, 0);
      acc[1][1] = __builtin_amdgcn_mfma_f32_16x16x32_bf16(a1, b1, acc[1][1], 0, 0, 0);
    }
    if (more) {
      ushort4 ab;
      ab.x = f2bf(av.x); ab.y = f2bf(av.y); ab.z = f2bf(av.z); ab.w = f2bf(av.w);
      *reinterpret_cast<ushort4*>((char*)&Asw[p ^ 1][0] + aoff) = ab;
    }
    __syncthreads();
    p ^= 1;
  }

  // epilogue: C/D layout col = l&15, row = (l>>4)*4 + q
#pragma unroll
  for (int m = 0; m < 2; ++m) {
#pragma unroll
    for (int n = 0; n < 2; ++n) {
#pragma unroll
      for (int q = 0; q < 4; ++q) {
        const int i = bm0 + m * 16 + (l >> 4) * 4 + q;
        const int f = wid * 32 + n * 16 + fr;
        const float selfv = bf2f(s2T[(size_t)f * NROW + i]);
        float v = (acc[m][n][q] + selfv) * D[i] + bias[f];
        out[(size_t)i * FOUTC + f] = fmaxf(v, 0.0f);
      }
    }
  }
}

extern "C" void kernel_launch(void* const* d_in, const int* in_sizes, int n_in,
                              void* d_out, int out_size, void* d_ws, size_t ws_size,
                              hipStream_t stream) {
  const float* x   = (const float*)d_in[0];
  const float* adj = (const float*)d_in[1];
  const float* W   = (const float*)d_in[2];
  const float* b   = (const float*)d_in[3];
  float* out = (float*)d_out;

  float* D = (float*)d_ws;                                                  // 32 KB
  unsigned short* s2T = (unsigned short*)((char*)d_ws + NROW * sizeof(float)); // 4 MB

  rowsum_kernel<<<NROW, 256, 0, stream>>>(adj, D);
  support_kernel<<<NROW / 32, 256, 0, stream>>>(x, W, D, s2T);
  gcn_gemm_kernel<<<NROW / BM, 512, 0, stream>>>(adj, s2T, D, b, out);
}

// Round 2
// 210.352 us; speedup vs baseline: 1.0892x; 1.0892x over previous
//
#include <hip/hip_runtime.h>
#include <hip/hip_bf16.h>

#define NROW 8192
#define FINC 256
#define FOUTC 256
#define BM 32
#define BK 64
#define NT (NROW / BK)   // 128

typedef __attribute__((ext_vector_type(8))) short bf16x8;
typedef __attribute__((ext_vector_type(4))) float f32x4;

__device__ __forceinline__ unsigned short f2bf(float f) {
  unsigned u = __float_as_uint(f);
  u += 0x7fffu + ((u >> 16) & 1u);   // round-to-nearest-even
  return (unsigned short)(u >> 16);
}
__device__ __forceinline__ float bf2f(unsigned short h) {
  return __uint_as_float(((unsigned)h) << 16);
}

// ---- kernel 1: D[i] = 1/sqrt(1 + sum_j adj[i][j]); one wave per row ----
__global__ __launch_bounds__(256) void rowsum_kernel(const float* __restrict__ adj,
                                                     float* __restrict__ D) {
  const int row = blockIdx.x * 4 + (threadIdx.x >> 6);
  const int l = threadIdx.x & 63;
  const float4* p = reinterpret_cast<const float4*>(adj + (size_t)row * NROW);
  float s0 = 0.f, s1 = 0.f, s2 = 0.f, s3 = 0.f;
#pragma unroll
  for (int i = 0; i < 8; ++i) {
    float4 a = p[l + (i * 4 + 0) * 64];
    float4 b = p[l + (i * 4 + 1) * 64];
    float4 c = p[l + (i * 4 + 2) * 64];
    float4 d = p[l + (i * 4 + 3) * 64];
    s0 += (a.x + a.y) + (a.z + a.w);
    s1 += (b.x + b.y) + (b.z + b.w);
    s2 += (c.x + c.y) + (c.z + c.w);
    s3 += (d.x + d.y) + (d.z + d.w);
  }
  float s = (s0 + s1) + (s2 + s3);
#pragma unroll
  for (int off = 32; off > 0; off >>= 1) s += __shfl_down(s, off, 64);
  if (l == 0) D[row] = 1.0f / sqrtf(s + 1.0f);
}

// ---- kernel 2: s2T[f][j] = bf16( D[j] * (x @ W)[j][f] ) ----
__global__ __launch_bounds__(256) void support_kernel(const float* __restrict__ x,
                                                      const float* __restrict__ W,
                                                      const float* __restrict__ D,
                                                      unsigned short* __restrict__ s2T) {
  __shared__ float xs[32][FINC];
  const int t = threadIdx.x;
  const int r0 = blockIdx.x * 32;
  {
    const float4* xg = reinterpret_cast<const float4*>(x + (size_t)r0 * FINC);
    float4* xl = reinterpret_cast<float4*>(&xs[0][0]);
#pragma unroll
    for (int i = 0; i < 8; ++i) xl[t + i * 256] = xg[t + i * 256];
  }
  __syncthreads();
  const int w = t >> 6, l = t & 63;
  float acc[8][4] = {};
  const float4* W4 = reinterpret_cast<const float4*>(W);
#pragma unroll 4
  for (int k = 0; k < FINC; ++k) {
    float4 wv = W4[k * 64 + l];
#pragma unroll
    for (int m = 0; m < 8; ++m) {
      float xv = xs[w * 8 + m][k];
      acc[m][0] = fmaf(xv, wv.x, acc[m][0]);
      acc[m][1] = fmaf(xv, wv.y, acc[m][1]);
      acc[m][2] = fmaf(xv, wv.z, acc[m][2]);
      acc[m][3] = fmaf(xv, wv.w, acc[m][3]);
    }
  }
#pragma unroll
  for (int m = 0; m < 8; ++m) {
    const int j = r0 + w * 8 + m;
    const float d = D[j];
    const int f0 = l * 4;
#pragma unroll
    for (int q = 0; q < 4; ++q)
      s2T[(size_t)(f0 + q) * NROW + j] = f2bf(d * acc[m][q]);
  }
}

// ---- kernel 3: out[i][f] = relu( D[i]*( sum_j adj[i][j]*s2T[f][j] + s2T[f][i] ) + b[f] )
// 3-stage circular LDS pipeline, counted vmcnt (never drains in main loop),
// raw s_barrier, loads issued post-barrier (clobber-safe vs stage t-1 readers).
__global__ __launch_bounds__(512) void gcn_gemm_kernel(const float* __restrict__ adj,
                                                       const unsigned short* __restrict__ s2T,
                                                       const float* __restrict__ D,
                                                       const float* __restrict__ bias,
                                                       float* __restrict__ out) {
  __shared__ __align__(16) unsigned short As[3][BM * BK];      // 3 x 4 KB bf16, XOR-swizzled
  __shared__ __align__(16) unsigned short Bs[3][FOUTC * BK];   // 3 x 32 KB bf16, XOR-swizzled

  const int t = threadIdx.x, wid = t >> 6, l = t & 63;
  const int bm0 = blockIdx.x * BM;

  // A staging: thread t -> row ar = t>>4, 4 consecutive fp32 at k0 = (t&15)*4
  const int ar = t >> 4;
  const unsigned awoff = (unsigned)(ar * 128 + (((t & 15) * 8) ^ ((ar & 7) << 4)));
  const float4* arow = reinterpret_cast<const float4*>(adj + (size_t)(bm0 + ar) * NROW) + (t & 15);

  // B staging via global_load_lds: lane l -> row c*8+(l>>3), pre-swizzled source kbyte
  const int bn = l >> 3;
  const unsigned bks = (unsigned)(((l & 7) * 16) ^ (bn << 4));

  f32x4 acc[2][2] = {};

  const unsigned swz = (unsigned)((l & 7) << 4);
  const int fr = l & 15;
  const unsigned kb = (unsigned)((l >> 4) * 16);
  const int nb = wid * 32;

  auto stageB = [&](int kt, int sl) {
#pragma unroll
    for (int i = 0; i < 4; ++i) {
      const int c = wid * 4 + i;
      const int n = c * 8 + bn;
      const unsigned short* src = s2T + (size_t)n * NROW + (size_t)kt * BK;
      __builtin_amdgcn_global_load_lds(
          (const __attribute__((address_space(1))) unsigned int*)((const char*)src + bks),
          (__attribute__((address_space(3))) unsigned int*)((char*)&Bs[sl][0] + c * 1024),
          16, 0, 0);
    }
  };
  auto writeA = [&](float4 av, int sl) {
    ushort4 ab;
    ab.x = f2bf(av.x); ab.y = f2bf(av.y); ab.z = f2bf(av.z); ab.w = f2bf(av.w);
    *reinterpret_cast<ushort4*>((char*)&As[sl][0] + awoff) = ab;
  };
  auto compute = [&](int sl) {
    const char* Ab = (const char*)&As[sl][0];
    const char* Bb = (const char*)&Bs[sl][0];
#pragma unroll
    for (int kk = 0; kk < 2; ++kk) {
      const unsigned kx = ((unsigned)(kk * 64) + kb) ^ swz;
      bf16x8 a0 = *reinterpret_cast<const bf16x8*>(Ab + fr * 128 + kx);
      bf16x8 a1 = *reinterpret_cast<const bf16x8*>(Ab + (fr + 16) * 128 + kx);
      bf16x8 b0 = *reinterpret_cast<const bf16x8*>(Bb + (nb + fr) * 128 + kx);
      bf16x8 b1 = *reinterpret_cast<const bf16x8*>(Bb + (nb + 16 + fr) * 128 + kx);
      acc[0][0] = __builtin_amdgcn_mfma_f32_16x16x32_bf16(a0, b0, acc[0][0], 0, 0, 0);
      acc[0][1] = __builtin_amdgcn_mfma_f32_16x16x32_bf16(a0, b1, acc[0][1], 0, 0, 0);
      acc[1][0] = __builtin_amdgcn_mfma_f32_16x16x32_bf16(a1, b0, acc[1][0], 0, 0, 0);
      acc[1][1] = __builtin_amdgcn_mfma_f32_16x16x32_bf16(a1, b1, acc[1][1], 0, 0, 0);
    }
  };

  // ---- prologue: windows fenced so vmcnt counting is exact ----
  // w(-3) = {A(0)} | w(-2) = {B(0)x4, A(1)} | w(-1) = {B(1)x4, A(2)}
  float4 aW, aF;
  {
    float4 a0v = arow[0];
    asm volatile("" ::: "memory");
    stageB(0, 0);
    aW = arow[16];
    asm volatile("" ::: "memory");
    stageB(1, 1);
    aF = arow[32];
    asm volatile("s_waitcnt vmcnt(10)" ::: "memory");  // A(0) arrived
    writeA(a0v, 0);
  }

  // ---- main loop: iter kt window = {B(kt+2)x4, A(kt+3)} = 5 vmem ops ----
  // top wait: window kt-2 done (B(kt) in LDS, A(kt+1) in reg), leave window kt-1 (5)
  int sc = 0, sn = 1, sn2 = 2;
#pragma unroll 1
  for (int kt = 0; kt < NT - 2; ++kt) {
    asm volatile("s_waitcnt vmcnt(5) lgkmcnt(0)\n\ts_barrier" ::: "memory");
    writeA(aW, sn);
    stageB(kt + 2, sn2);
    float4 aN = aF;
    if (kt < NT - 3) aN = arow[(kt + 3) * 16];
    compute(sc);
    aW = aF; aF = aN;
    int tmp = sc; sc = sn; sn = sn2; sn2 = tmp;
  }
  // kt = NT-2: in flight w(NT-4)={B(NT-2)x4,A(NT-1)}(5), w(NT-3)={B(NT-1)x4}(4)
  asm volatile("s_waitcnt vmcnt(4) lgkmcnt(0)\n\ts_barrier" ::: "memory");
  writeA(aW, sn);
  compute(sc);
  { int tmp = sc; sc = sn; sn = sn2; sn2 = tmp; }
  // kt = NT-1: only w(NT-3) outstanding
  asm volatile("s_waitcnt vmcnt(0) lgkmcnt(0)\n\ts_barrier" ::: "memory");
  compute(sc);

  // ---- epilogue: C/D layout col = l&15, row = (l>>4)*4 + q ----
#pragma unroll
  for (int m = 0; m < 2; ++m) {
#pragma unroll
    for (int n = 0; n < 2; ++n) {
#pragma unroll
      for (int q = 0; q < 4; ++q) {
        const int i = bm0 + m * 16 + (l >> 4) * 4 + q;
        const int f = wid * 32 + n * 16 + fr;
        const float selfv = bf2f(s2T[(size_t)f * NROW + i]);
        float v = (acc[m][n][q] + selfv) * D[i] + bias[f];
        out[(size_t)i * FOUTC + f] = fmaxf(v, 0.0f);
      }
    }
  }
}

extern "C" void kernel_launch(void* const* d_in, const int* in_sizes, int n_in,
                              void* d_out, int out_size, void* d_ws, size_t ws_size,
                              hipStream_t stream) {
  const float* x   = (const float*)d_in[0];
  const float* adj = (const float*)d_in[1];
  const float* W   = (const float*)d_in[2];
  const float* b   = (const float*)d_in[3];
  float* out = (float*)d_out;

  float* D = (float*)d_ws;                                                     // 32 KB
  unsigned short* s2T = (unsigned short*)((char*)d_ws + NROW * sizeof(float)); // 4 MB

  rowsum_kernel<<<NROW / 4, 256, 0, stream>>>(adj, D);
  support_kernel<<<NROW / 32, 256, 0, stream>>>(x, W, D, s2T);
  gcn_gemm_kernel<<<NROW / BM, 512, 0, stream>>>(adj, s2T, D, b, out);
}

// Round 3
// 201.859 us; speedup vs baseline: 1.1350x; 1.0421x over previous
//
#include <hip/hip_runtime.h>
#include <hip/hip_bf16.h>

#define NROW 8192
#define FINC 256
#define FOUTC 256
#define BM 32
#define BK 64
#define NT (NROW / BK)   // 128

typedef __attribute__((ext_vector_type(8))) short bf16x8;
typedef __attribute__((ext_vector_type(4))) float f32x4;

__device__ __forceinline__ unsigned short f2bf(float f) {
  unsigned u = __float_as_uint(f);
  u += 0x7fffu + ((u >> 16) & 1u);   // round-to-nearest-even
  return (unsigned short)(u >> 16);
}
__device__ __forceinline__ float bf2f(unsigned short h) {
  return __uint_as_float(((unsigned)h) << 16);
}

// ---- kernel 1: D[i] = 1/sqrt(1 + sum_j adj[i][j]); one wave per row ----
__global__ __launch_bounds__(256) void rowsum_kernel(const float* __restrict__ adj,
                                                     float* __restrict__ D) {
  const int row = blockIdx.x * 4 + (threadIdx.x >> 6);
  const int l = threadIdx.x & 63;
  const float4* p = reinterpret_cast<const float4*>(adj + (size_t)row * NROW);
  float s0 = 0.f, s1 = 0.f, s2 = 0.f, s3 = 0.f;
#pragma unroll
  for (int i = 0; i < 8; ++i) {
    float4 a = p[l + (i * 4 + 0) * 64];
    float4 b = p[l + (i * 4 + 1) * 64];
    float4 c = p[l + (i * 4 + 2) * 64];
    float4 d = p[l + (i * 4 + 3) * 64];
    s0 += (a.x + a.y) + (a.z + a.w);
    s1 += (b.x + b.y) + (b.z + b.w);
    s2 += (c.x + c.y) + (c.z + c.w);
    s3 += (d.x + d.y) + (d.z + d.w);
  }
  float s = (s0 + s1) + (s2 + s3);
#pragma unroll
  for (int off = 32; off > 0; off >>= 1) s += __shfl_down(s, off, 64);
  if (l == 0) D[row] = 1.0f / sqrtf(s + 1.0f);
}

// ---- kernel 2: s2T[f][j] = bf16( D[j] * (x @ W)[j][f] ) ----
__global__ __launch_bounds__(256) void support_kernel(const float* __restrict__ x,
                                                      const float* __restrict__ W,
                                                      const float* __restrict__ D,
                                                      unsigned short* __restrict__ s2T) {
  __shared__ float xs[32][FINC];
  const int t = threadIdx.x;
  const int r0 = blockIdx.x * 32;
  {
    const float4* xg = reinterpret_cast<const float4*>(x + (size_t)r0 * FINC);
    float4* xl = reinterpret_cast<float4*>(&xs[0][0]);
#pragma unroll
    for (int i = 0; i < 8; ++i) xl[t + i * 256] = xg[t + i * 256];
  }
  __syncthreads();
  const int w = t >> 6, l = t & 63;
  float acc[8][4] = {};
  const float4* W4 = reinterpret_cast<const float4*>(W);
#pragma unroll 4
  for (int k = 0; k < FINC; ++k) {
    float4 wv = W4[k * 64 + l];
#pragma unroll
    for (int m = 0; m < 8; ++m) {
      float xv = xs[w * 8 + m][k];
      acc[m][0] = fmaf(xv, wv.x, acc[m][0]);
      acc[m][1] = fmaf(xv, wv.y, acc[m][1]);
      acc[m][2] = fmaf(xv, wv.z, acc[m][2]);
      acc[m][3] = fmaf(xv, wv.w, acc[m][3]);
    }
  }
#pragma unroll
  for (int m = 0; m < 8; ++m) {
    const int j = r0 + w * 8 + m;
    const float d = D[j];
    const int f0 = l * 4;
#pragma unroll
    for (int q = 0; q < 4; ++q)
      s2T[(size_t)(f0 + q) * NROW + j] = f2bf(d * acc[m][q]);
  }
}

// ---- kernel 3: out[i][f] = relu( D[i]*( sum_j adj[i][j]*s2T[f][j] + s2T[f][i] ) + b[f] )
// 3-stage circular LDS pipeline, counted vmcnt, raw s_barrier, loads issued
// post-barrier. Hand-unrolled x3 so slot indices are literals and the A-prefetch
// registers are loop-carried under the SAME names (no phi moves -> no vmcnt(0)
// drain at the back edge; that drain was the round-2 regression).
__global__ __launch_bounds__(512) void gcn_gemm_kernel(const float* __restrict__ adj,
                                                       const unsigned short* __restrict__ s2T,
                                                       const float* __restrict__ D,
                                                       const float* __restrict__ bias,
                                                       float* __restrict__ out) {
  __shared__ __align__(16) unsigned short As[3][BM * BK];      // 3 x 4 KB bf16, XOR-swizzled
  __shared__ __align__(16) unsigned short Bs[3][FOUTC * BK];   // 3 x 32 KB bf16, XOR-swizzled

  const int t = threadIdx.x, wid = t >> 6, l = t & 63;
  const int bm0 = blockIdx.x * BM;

  // A staging: thread t -> row ar = t>>4, 4 consecutive fp32 at k0 = (t&15)*4
  const int ar = t >> 4;
  const unsigned awoff = (unsigned)(ar * 128 + (((t & 15) * 8) ^ ((ar & 7) << 4)));
  const float4* arow = reinterpret_cast<const float4*>(adj + (size_t)(bm0 + ar) * NROW) + (t & 15);

  // B staging via global_load_lds: lane l -> row c*8+(l>>3), pre-swizzled source kbyte
  const int bn = l >> 3;
  const unsigned bks = (unsigned)(((l & 7) * 16) ^ (bn << 4));

  f32x4 acc[2][2] = {};

  const unsigned swz = (unsigned)((l & 7) << 4);
  const int fr = l & 15;
  const unsigned kb = (unsigned)((l >> 4) * 16);
  const int nb = wid * 32;

  auto stageB = [&](int kt, int sl) {
#pragma unroll
    for (int i = 0; i < 4; ++i) {
      const int c = wid * 4 + i;
      const int n = c * 8 + bn;
      const unsigned short* src = s2T + (size_t)n * NROW + (size_t)kt * BK;
      __builtin_amdgcn_global_load_lds(
          (const __attribute__((address_space(1))) unsigned int*)((const char*)src + bks),
          (__attribute__((address_space(3))) unsigned int*)((char*)&Bs[sl][0] + c * 1024),
          16, 0, 0);
    }
  };
  auto writeA = [&](float4 av, int sl) {
    ushort4 ab;
    ab.x = f2bf(av.x); ab.y = f2bf(av.y); ab.z = f2bf(av.z); ab.w = f2bf(av.w);
    *reinterpret_cast<ushort4*>((char*)&As[sl][0] + awoff) = ab;
  };
  auto compute = [&](int sl) {
    const char* Ab = (const char*)&As[sl][0];
    const char* Bb = (const char*)&Bs[sl][0];
#pragma unroll
    for (int kk = 0; kk < 2; ++kk) {
      const unsigned kx = ((unsigned)(kk * 64) + kb) ^ swz;
      bf16x8 a0 = *reinterpret_cast<const bf16x8*>(Ab + fr * 128 + kx);
      bf16x8 a1 = *reinterpret_cast<const bf16x8*>(Ab + (fr + 16) * 128 + kx);
      bf16x8 b0 = *reinterpret_cast<const bf16x8*>(Bb + (nb + fr) * 128 + kx);
      bf16x8 b1 = *reinterpret_cast<const bf16x8*>(Bb + (nb + 16 + fr) * 128 + kx);
      acc[0][0] = __builtin_amdgcn_mfma_f32_16x16x32_bf16(a0, b0, acc[0][0], 0, 0, 0);
      acc[0][1] = __builtin_amdgcn_mfma_f32_16x16x32_bf16(a0, b1, acc[0][1], 0, 0, 0);
      acc[1][0] = __builtin_amdgcn_mfma_f32_16x16x32_bf16(a1, b0, acc[1][0], 0, 0, 0);
      acc[1][1] = __builtin_amdgcn_mfma_f32_16x16x32_bf16(a1, b1, acc[1][1], 0, 0, 0);
    }
  };

  // ---- prologue: windows fenced so vmcnt counting is exact ----
  // w(-3) = {A(0)} | w(-2) = {B(0)x4, A(1)->a1p} | w(-1) = {B(1)x4, A(2)->a2p}
  float4 a0p, a1p, a2p;
  {
    float4 a0v = arow[0];
    asm volatile("" ::: "memory");
    stageB(0, 0);
    a1p = arow[16];
    asm volatile("" ::: "memory");
    stageB(1, 1);
    a2p = arow[32];
    asm volatile("s_waitcnt vmcnt(10)" ::: "memory");  // A(0) arrived
    writeA(a0v, 0);
  }

  // ---- main loop: iter kt window = {B(kt+2)x4, A(kt+3)} = 5 vmem ops ----
  // Top wait: windows <= kt-2 done (B(kt) in LDS, A(kt+1) in reg); window kt-1
  // (5 ops) stays in flight. Sub-iter KT (KT%3==r): compute slot r, writeA
  // A(KT+1) from aP[(KT+1)%3] to slot (KT+1)%3, stageB(KT+2) to slot (KT+2)%3,
  // load A(KT+3) into aP[KT%3].
#define PIPE_ITER(KT, S0, S1, S2, AW, AN)                                      \
  asm volatile("s_waitcnt vmcnt(5) lgkmcnt(0)\n\ts_barrier" ::: "memory");     \
  writeA(AW, S1);                                                              \
  stageB((KT) + 2, S2);                                                        \
  if ((KT) < NT - 3) AN = arow[((KT) + 3) * 16];                               \
  compute(S0);

#pragma unroll 1
  for (int kt = 0; kt < NT - 2; kt += 3) {
    PIPE_ITER(kt + 0, 0, 1, 2, a1p, a0p)
    PIPE_ITER(kt + 1, 1, 2, 0, a2p, a1p)
    PIPE_ITER(kt + 2, 2, 0, 1, a0p, a2p)
  }
#undef PIPE_ITER

  // kt = NT-2 (==126, slot 0): in flight w(NT-4)={B(NT-2)x4,A(NT-1)}(5),
  // w(NT-3)={B(NT-1)x4}(4, A skipped by guard)
  asm volatile("s_waitcnt vmcnt(4) lgkmcnt(0)\n\ts_barrier" ::: "memory");
  writeA(a1p, 1);   // A(NT-1) -> slot (NT-1)%3 == 1
  compute(0);
  // kt = NT-1 (slot 1): only w(NT-3) outstanding
  asm volatile("s_waitcnt vmcnt(0) lgkmcnt(0)\n\ts_barrier" ::: "memory");
  compute(1);

  // ---- epilogue: C/D layout col = l&15, row = (l>>4)*4 + q ----
#pragma unroll
  for (int m = 0; m < 2; ++m) {
#pragma unroll
    for (int n = 0; n < 2; ++n) {
#pragma unroll
      for (int q = 0; q < 4; ++q) {
        const int i = bm0 + m * 16 + (l >> 4) * 4 + q;
        const int f = wid * 32 + n * 16 + fr;
        const float selfv = bf2f(s2T[(size_t)f * NROW + i]);
        float v = (acc[m][n][q] + selfv) * D[i] + bias[f];
        out[(size_t)i * FOUTC + f] = fmaxf(v, 0.0f);
      }
    }
  }
}

extern "C" void kernel_launch(void* const* d_in, const int* in_sizes, int n_in,
                              void* d_out, int out_size, void* d_ws, size_t ws_size,
                              hipStream_t stream) {
  const float* x   = (const float*)d_in[0];
  const float* adj = (const float*)d_in[1];
  const float* W   = (const float*)d_in[2];
  const float* b   = (const float*)d_in[3];
  float* out = (float*)d_out;

  float* D = (float*)d_ws;                                                     // 32 KB
  unsigned short* s2T = (unsigned short*)((char*)d_ws + NROW * sizeof(float)); // 4 MB

  rowsum_kernel<<<NROW / 4, 256, 0, stream>>>(adj, D);
  support_kernel<<<NROW / 32, 256, 0, stream>>>(x, W, D, s2T);
  gcn_gemm_kernel<<<NROW / BM, 512, 0, stream>>>(adj, s2T, D, b, out);
}